// Round 1
// baseline (309.277 us; speedup 1.0000x reference)
//
#include <hip/hip_runtime.h>

// Problem: B=2, T=2048, D_MODEL=1024, H=16, Dh=64.  out = MHA_ALiBi(x) @ Wo^T
// Pipeline: cvt->bf16 | QKV proj GEMMs (MFMA) | flash attn (MFMA, online softmax,
// exp2 domain) | O proj GEMM (fp32 out).

#define DEV __device__ __forceinline__

typedef __attribute__((ext_vector_type(8))) short short8;     // 8 bf16 (4 VGPRs)
typedef __attribute__((ext_vector_type(4))) float f32x4;      // MFMA C/D
typedef __attribute__((ext_vector_type(4))) unsigned short ushort4v;

DEV unsigned short f2bf(float f) {                            // RNE fp32->bf16
  unsigned u = __builtin_bit_cast(unsigned, f);
  u += 0x7fffu + ((u >> 16) & 1u);
  return (unsigned short)(u >> 16);
}

DEV void gl2lds16(const void* g, void* l) {                   // 16B direct-to-LDS
  __builtin_amdgcn_global_load_lds(
      (const __attribute__((address_space(1))) void*)g,
      (__attribute__((address_space(3))) void*)l, 16, 0, 0);
}

// ---------------- fp32 -> bf16 convert (n multiple of 1024) ----------------
__global__ __launch_bounds__(256) void cvt_bf16(const float* __restrict__ s,
                                                unsigned short* __restrict__ d) {
  int i = (blockIdx.x * 256 + threadIdx.x) * 4;
  float4 v = *(const float4*)(s + i);
  ushort4v o = {f2bf(v.x), f2bf(v.y), f2bf(v.z), f2bf(v.w)};
  *(ushort4v*)(d + i) = o;
}

// ---------------- GEMM: C[m,n] = sum_k A[m,k]*B[n,k]  (both K-major) -------
// 128x128 tile, BK=32, 4 waves each 64x64 (4x4 of 16x16x32 MFMA). K=1024 fixed.
// MODE 0: Q epilogue (scale by log2e/8, bf16, (z,t,d) layout)
// MODE 1: K epilogue (bf16, (z,t,d))
// MODE 2: V epilogue (bf16, TRANSPOSED (z,d,t))
// MODE 3: fp32 row-major out (final projection)
template <int MODE>
__global__ __launch_bounds__(256, 2) void gemm_bt(
    const unsigned short* __restrict__ A, const unsigned short* __restrict__ Bm,
    void* __restrict__ Cv) {
  constexpr int K = 1024;
  __shared__ alignas(16) unsigned short Al[128 * 32];
  __shared__ alignas(16) unsigned short Bl[128 * 32];
  const int t = threadIdx.x;
  const int l = t & 63, l15 = l & 15, l4 = l >> 4;
  const int wm = ((t >> 6) & 1) * 64, wn = (t >> 7) * 64;
  const int m0 = blockIdx.y * 128, n0 = blockIdx.x * 128;

  f32x4 zero4 = {0.f, 0.f, 0.f, 0.f};
  f32x4 acc[4][4];
#pragma unroll
  for (int i = 0; i < 4; i++)
#pragma unroll
    for (int j = 0; j < 4; j++) acc[i][j] = zero4;

  const int row0 = t >> 2, seg = (t & 3) * 8;
  const unsigned short* Ag0 = A + (m0 + row0) * K + seg;
  const unsigned short* Ag1 = A + (m0 + row0 + 64) * K + seg;
  const unsigned short* Bg0 = Bm + (n0 + row0) * K + seg;
  const unsigned short* Bg1 = Bm + (n0 + row0 + 64) * K + seg;

  for (int k0 = 0; k0 < K; k0 += 32) {
    gl2lds16(Ag0 + k0, &Al[t * 8]);
    gl2lds16(Ag1 + k0, &Al[2048 + t * 8]);
    gl2lds16(Bg0 + k0, &Bl[t * 8]);
    gl2lds16(Bg1 + k0, &Bl[2048 + t * 8]);
    __syncthreads();
    short8 af[4], bf8[4];
#pragma unroll
    for (int mi = 0; mi < 4; mi++)
      af[mi] = *(const short8*)&Al[(wm + mi * 16 + l15) * 32 + l4 * 8];
#pragma unroll
    for (int ni = 0; ni < 4; ni++)
      bf8[ni] = *(const short8*)&Bl[(wn + ni * 16 + l15) * 32 + l4 * 8];
#pragma unroll
    for (int mi = 0; mi < 4; mi++)
#pragma unroll
      for (int ni = 0; ni < 4; ni++)
        acc[mi][ni] = __builtin_amdgcn_mfma_f32_16x16x32_bf16(
            af[mi], bf8[ni], acc[mi][ni], 0, 0, 0);
    __syncthreads();
  }

  // Epilogue. C/D layout: col = l&15, row = (l>>4)*4 + r  [m89/m91]
  if (MODE == 3) {
    float* C = (float*)Cv;
#pragma unroll
    for (int mi = 0; mi < 4; mi++)
#pragma unroll
      for (int r = 0; r < 4; r++) {
        int m = m0 + wm + mi * 16 + l4 * 4 + r;
        float* cp = C + m * 1024 + n0 + wn + l15;
#pragma unroll
        for (int ni = 0; ni < 4; ni++) cp[ni * 16] = acc[mi][ni][r];
      }
  } else {
    unsigned short* D = (unsigned short*)Cv;
#pragma unroll
    for (int mi = 0; mi < 4; mi++)
#pragma unroll
      for (int r = 0; r < 4; r++) {
        int m = m0 + wm + mi * 16 + l4 * 4 + r;
        int b = m >> 11, tt = m & 2047;
#pragma unroll
        for (int ni = 0; ni < 4; ni++) {
          int n = n0 + wn + ni * 16 + l15;
          int z = b * 16 + (n >> 6), d = n & 63;
          float v = acc[mi][ni][r];
          if (MODE == 0) v *= 0.18033688011112042f;  // log2(e)/8 folded into Q
          int idx = (MODE == 2) ? ((z * 64 + d) * 2048 + tt)
                                : ((z * 2048 + tt) * 64 + d);
          D[idx] = f2bf(v);
        }
      }
  }
}

// ---------------- Flash attention with causal ALiBi ------------------------
// grid (T/128=16 q-tiles, B*H=32). Block 256 = 4 waves, wave w owns 32 q-rows.
// K LDS layout: (d-half ks)[2] x kv[64] x d32  (64B rows, m97 pattern)
// V LDS layout: (kv-half ks)[2] x d[64] x kv32
// P LDS: per-wave 32 x 72 (pad 8 -> 144B rows: 16B-aligned, conflict-free)
__global__ __launch_bounds__(256, 2) void flash_alibi(
    const unsigned short* __restrict__ Q, const unsigned short* __restrict__ Kb,
    const unsigned short* __restrict__ Vt, unsigned short* __restrict__ O) {
  __shared__ alignas(16) unsigned short Kl[4096];
  __shared__ alignas(16) unsigned short Vl[4096];
  __shared__ alignas(16) unsigned short Pl[4 * 32 * 72];
  const int t = threadIdx.x, w = t >> 6, l = t & 63, l15 = l & 15, l4 = l >> 4;
  const int z = blockIdx.y, q0 = blockIdx.x * 128;
  const int h = z & 15;
  // p = exp2(S2 + bias2 - m2); S2 has log2e/8 folded in Q; bias2 = -dist*slope*log2e
  const float slope2 = exp2f(-0.5f * (float)(h + 1)) * 1.4426950408889634f;

  const int qrow = q0 + w * 32;
  short8 aq[2][2];
#pragma unroll
  for (int mi = 0; mi < 2; mi++)
#pragma unroll
    for (int ks = 0; ks < 2; ks++)
      aq[mi][ks] = *(const short8*)&Q[(z * 2048 + qrow + mi * 16 + l15) * 64 +
                                      ks * 32 + l4 * 8];

  f32x4 zero4 = {0.f, 0.f, 0.f, 0.f};
  f32x4 o[2][4];
  float mst[2][4], lst[2][4];
#pragma unroll
  for (int mi = 0; mi < 2; mi++)
#pragma unroll
    for (int j = 0; j < 4; j++) {
      o[mi][j] = zero4;
      mst[mi][j] = -1e30f;
      lst[mi][j] = 0.f;
    }

  const int row0 = t >> 2, seg8 = (t & 3) * 8;
  const int kvtiles = q0 / 64 + 2;  // only kv0 <= q0+127 (causal)

  for (int it = 0; it < kvtiles; it++) {
    const int kv0 = it * 64;
    {
      int lr0 = row0, lr1 = row0 + 64;
      gl2lds16(&Kb[(z * 2048 + kv0 + (lr0 & 63)) * 64 + (lr0 >> 6) * 32 + seg8],
               &Kl[t * 8]);
      gl2lds16(&Kb[(z * 2048 + kv0 + (lr1 & 63)) * 64 + (lr1 >> 6) * 32 + seg8],
               &Kl[2048 + t * 8]);
      gl2lds16(&Vt[(z * 64 + (lr0 & 63)) * 2048 + kv0 + (lr0 >> 6) * 32 + seg8],
               &Vl[t * 8]);
      gl2lds16(&Vt[(z * 64 + (lr1 & 63)) * 2048 + kv0 + (lr1 >> 6) * 32 + seg8],
               &Vl[2048 + t * 8]);
    }
    __syncthreads();

    // S = Q K^T  (rows q, cols kv)
    f32x4 s[2][4];
#pragma unroll
    for (int mi = 0; mi < 2; mi++)
#pragma unroll
      for (int ni = 0; ni < 4; ni++) s[mi][ni] = zero4;
#pragma unroll
    for (int ks = 0; ks < 2; ks++) {
      short8 bk[4];
#pragma unroll
      for (int ni = 0; ni < 4; ni++)
        bk[ni] = *(const short8*)&Kl[(ks * 64 + ni * 16 + l15) * 32 + l4 * 8];
#pragma unroll
      for (int mi = 0; mi < 2; mi++)
#pragma unroll
        for (int ni = 0; ni < 4; ni++)
          s[mi][ni] = __builtin_amdgcn_mfma_f32_16x16x32_bf16(
              aq[mi][ks], bk[ni], s[mi][ni], 0, 0, 0);
    }

    // online softmax (exp2 domain), write P (bf16) to per-wave LDS region
#pragma unroll
    for (int mi = 0; mi < 2; mi++)
#pragma unroll
      for (int r = 0; r < 4; r++) {
        int qi = qrow + mi * 16 + l4 * 4 + r;
        float v[4];
#pragma unroll
        for (int ni = 0; ni < 4; ni++) {
          int j = kv0 + ni * 16 + l15;
          int dj = qi - j;
          float sv = s[mi][ni][r];
          v[ni] = (dj >= 0) ? fmaf(-slope2, (float)dj, sv) : -1e30f;
        }
        float mx = fmaxf(fmaxf(v[0], v[1]), fmaxf(v[2], v[3]));
#pragma unroll
        for (int off = 1; off < 16; off <<= 1)
          mx = fmaxf(mx, __shfl_xor(mx, off));
        float mo = mst[mi][r];
        float mn = fmaxf(mo, mx);
        float alpha = __builtin_amdgcn_exp2f(mo - mn);
        float rs = 0.f;
        unsigned short pb[4];
#pragma unroll
        for (int ni = 0; ni < 4; ni++) {
          float p = __builtin_amdgcn_exp2f(v[ni] - mn);
          rs += p;
          pb[ni] = f2bf(p);
        }
#pragma unroll
        for (int off = 1; off < 16; off <<= 1) rs += __shfl_xor(rs, off);
        lst[mi][r] = lst[mi][r] * alpha + rs;
        mst[mi][r] = mn;
#pragma unroll
        for (int nd = 0; nd < 4; nd++) o[mi][nd][r] *= alpha;
        unsigned short* pp = &Pl[w * 2304 + (mi * 16 + l4 * 4 + r) * 72 + l15];
#pragma unroll
        for (int ni = 0; ni < 4; ni++) pp[ni * 16] = pb[ni];
      }
    __syncthreads();  // conservative: P LDS write->read + keep waves together

    // O += P @ V   (P: A-operand from LDS round-trip [m120]; V: B-operand)
#pragma unroll
    for (int ks = 0; ks < 2; ks++) {
      short8 pf[2], vf[4];
#pragma unroll
      for (int mi = 0; mi < 2; mi++)
        pf[mi] = *(const short8*)&Pl[w * 2304 + (mi * 16 + l15) * 72 + ks * 32 +
                                     l4 * 8];
#pragma unroll
      for (int nd = 0; nd < 4; nd++)
        vf[nd] = *(const short8*)&Vl[(ks * 64 + nd * 16 + l15) * 32 + l4 * 8];
#pragma unroll
      for (int mi = 0; mi < 2; mi++)
#pragma unroll
        for (int nd = 0; nd < 4; nd++)
          o[mi][nd] = __builtin_amdgcn_mfma_f32_16x16x32_bf16(
              pf[mi], vf[nd], o[mi][nd], 0, 0, 0);
    }
    __syncthreads();  // protect Kl/Vl before next stage
  }

  // epilogue: O/l, bf16, (b, t, h*64+d) layout
  const int bq = z >> 4, hh = z & 15;
#pragma unroll
  for (int mi = 0; mi < 2; mi++)
#pragma unroll
    for (int r = 0; r < 4; r++) {
      int tg = qrow + mi * 16 + l4 * 4 + r;
      float inv = 1.0f / lst[mi][r];
      unsigned short* op = &O[(bq * 2048 + tg) * 1024 + hh * 64 + l15];
#pragma unroll
      for (int nd = 0; nd < 4; nd++) op[nd * 16] = f2bf(o[mi][nd][r] * inv);
    }
}

// ---------------------------------------------------------------------------
extern "C" void kernel_launch(void* const* d_in, const int* in_sizes, int n_in,
                              void* d_out, int out_size, void* d_ws,
                              size_t ws_size, hipStream_t stream) {
  const float* x = (const float*)d_in[0];
  const float* Wq = (const float*)d_in[1];
  const float* Wk = (const float*)d_in[2];
  const float* Wv = (const float*)d_in[3];
  const float* Wo = (const float*)d_in[4];

  char* p = (char*)d_ws;
  unsigned short* xb = (unsigned short*)p;  p += 4096 * 1024 * 2;
  unsigned short* wqb = (unsigned short*)p; p += 1024 * 1024 * 2;
  unsigned short* wkb = (unsigned short*)p; p += 1024 * 1024 * 2;
  unsigned short* wvb = (unsigned short*)p; p += 1024 * 1024 * 2;
  unsigned short* wob = (unsigned short*)p; p += 1024 * 1024 * 2;
  unsigned short* Qb = (unsigned short*)p;  p += 32 * 2048 * 64 * 2;
  unsigned short* Kbf = (unsigned short*)p; p += 32 * 2048 * 64 * 2;
  unsigned short* Vtb = (unsigned short*)p; p += 32 * 2048 * 64 * 2;
  unsigned short* Ob = (unsigned short*)p;  p += 4096 * 1024 * 2;
  // total ws use: 48 MiB

  cvt_bf16<<<4096, 256, 0, stream>>>(x, xb);
  cvt_bf16<<<1024, 256, 0, stream>>>(Wq, wqb);
  cvt_bf16<<<1024, 256, 0, stream>>>(Wk, wkb);
  cvt_bf16<<<1024, 256, 0, stream>>>(Wv, wvb);
  cvt_bf16<<<1024, 256, 0, stream>>>(Wo, wob);

  dim3 g(8, 32);
  gemm_bt<0><<<g, 256, 0, stream>>>(xb, wqb, (void*)Qb);
  gemm_bt<1><<<g, 256, 0, stream>>>(xb, wkb, (void*)Kbf);
  gemm_bt<2><<<g, 256, 0, stream>>>(xb, wvb, (void*)Vtb);

  flash_alibi<<<dim3(16, 32), 256, 0, stream>>>(Qb, Kbf, Vtb, Ob);

  gemm_bt<3><<<g, 256, 0, stream>>>(Ob, wob, d_out);
}

// Round 2
// 201.680 us; speedup vs baseline: 1.5335x; 1.5335x over previous
//
#include <hip/hip_runtime.h>

// B=2, T=2048, D_MODEL=1024, H=16, Dh=64.  out = MHA_ALiBi(x) @ Wo^T
// cvt->bf16 (1 kernel) | fused QKV GEMM | flash attn (static-margin exp2
// softmax, separable ALiBi, K/V dbuf, 1 barrier/tile) | O proj (fp32 out).

#define DEV __device__ __forceinline__

typedef __attribute__((ext_vector_type(8))) short short8;     // 8 bf16
typedef __attribute__((ext_vector_type(4))) float f32x4;      // MFMA C/D
typedef __attribute__((ext_vector_type(4))) unsigned short ushort4v;

DEV unsigned short f2bf(float f) {                            // RNE fp32->bf16
  unsigned u = __builtin_bit_cast(unsigned, f);
  u += 0x7fffu + ((u >> 16) & 1u);
  return (unsigned short)(u >> 16);
}

DEV void gl2lds16(const void* g, void* l) {                   // 16B direct-to-LDS
  __builtin_amdgcn_global_load_lds(
      (const __attribute__((address_space(1))) void*)g,
      (__attribute__((address_space(3))) void*)l, 16, 0, 0);
}

// ---------------- fused fp32 -> bf16 convert (x + 4 weights) ---------------
__global__ __launch_bounds__(256) void cvt_all(
    const float* __restrict__ x, const float* __restrict__ wq,
    const float* __restrict__ wk, const float* __restrict__ wv,
    const float* __restrict__ wo, unsigned short* __restrict__ xb,
    unsigned short* __restrict__ wqb, unsigned short* __restrict__ wkb,
    unsigned short* __restrict__ wvb, unsigned short* __restrict__ wob) {
  int b = blockIdx.x;
  const float* s;
  unsigned short* d;
  int off;
  if (b < 4096)      { s = x;  d = xb;  off = b; }
  else if (b < 5120) { s = wq; d = wqb; off = b - 4096; }
  else if (b < 6144) { s = wk; d = wkb; off = b - 5120; }
  else if (b < 7168) { s = wv; d = wvb; off = b - 6144; }
  else               { s = wo; d = wob; off = b - 7168; }
  int i = (off * 256 + threadIdx.x) * 4;
  float4 v = *(const float4*)(s + i);
  ushort4v o = {f2bf(v.x), f2bf(v.y), f2bf(v.z), f2bf(v.w)};
  *(ushort4v*)(d + i) = o;
}

// ---------------- fused QKV GEMM: C[m,n] = sum_k A[m,k]*W[n,k] -------------
// grid (24, 32): x = wsel*8 + ntile. 128x128 tile, BK=32, m97 structure.
// wsel 0: Q (scale log2e/8, (z,t,d)) | 1: K ((z,t,d)) | 2: V transposed (z,d,t)
__global__ __launch_bounds__(256, 2) void gemm_qkv(
    const unsigned short* __restrict__ A, const unsigned short* __restrict__ Wq,
    const unsigned short* __restrict__ Wk, const unsigned short* __restrict__ Wv,
    unsigned short* __restrict__ Qo, unsigned short* __restrict__ Ko,
    unsigned short* __restrict__ Vo) {
  constexpr int K = 1024;
  __shared__ alignas(16) unsigned short Al[128 * 32];
  __shared__ alignas(16) unsigned short Bl[128 * 32];
  const int t = threadIdx.x;
  const int l = t & 63, l15 = l & 15, l4 = l >> 4;
  const int wm = ((t >> 6) & 1) * 64, wn = (t >> 7) * 64;
  const int wsel = blockIdx.x >> 3;
  const int n0 = (blockIdx.x & 7) * 128;
  const int m0 = blockIdx.y * 128;
  const unsigned short* Bm = (wsel == 0) ? Wq : ((wsel == 1) ? Wk : Wv);

  f32x4 zero4 = {0.f, 0.f, 0.f, 0.f};
  f32x4 acc[4][4];
#pragma unroll
  for (int i = 0; i < 4; i++)
#pragma unroll
    for (int j = 0; j < 4; j++) acc[i][j] = zero4;

  const int row0 = t >> 2, seg = (t & 3) * 8;
  const unsigned short* Ag0 = A + (m0 + row0) * K + seg;
  const unsigned short* Ag1 = A + (m0 + row0 + 64) * K + seg;
  const unsigned short* Bg0 = Bm + (n0 + row0) * K + seg;
  const unsigned short* Bg1 = Bm + (n0 + row0 + 64) * K + seg;

  for (int k0 = 0; k0 < K; k0 += 32) {
    gl2lds16(Ag0 + k0, &Al[t * 8]);
    gl2lds16(Ag1 + k0, &Al[2048 + t * 8]);
    gl2lds16(Bg0 + k0, &Bl[t * 8]);
    gl2lds16(Bg1 + k0, &Bl[2048 + t * 8]);
    __syncthreads();
    short8 af[4], bf8[4];
#pragma unroll
    for (int mi = 0; mi < 4; mi++)
      af[mi] = *(const short8*)&Al[(wm + mi * 16 + l15) * 32 + l4 * 8];
#pragma unroll
    for (int ni = 0; ni < 4; ni++)
      bf8[ni] = *(const short8*)&Bl[(wn + ni * 16 + l15) * 32 + l4 * 8];
#pragma unroll
    for (int mi = 0; mi < 4; mi++)
#pragma unroll
      for (int ni = 0; ni < 4; ni++)
        acc[mi][ni] = __builtin_amdgcn_mfma_f32_16x16x32_bf16(
            af[mi], bf8[ni], acc[mi][ni], 0, 0, 0);
    __syncthreads();
  }

  unsigned short* D = (wsel == 0) ? Qo : ((wsel == 1) ? Ko : Vo);
  const float scale = (wsel == 0) ? 0.18033688011112042f : 1.0f;  // log2e/8
#pragma unroll
  for (int mi = 0; mi < 4; mi++)
#pragma unroll
    for (int r = 0; r < 4; r++) {
      int m = m0 + wm + mi * 16 + l4 * 4 + r;
      int b = m >> 11, tt = m & 2047;
#pragma unroll
      for (int ni = 0; ni < 4; ni++) {
        int n = n0 + wn + ni * 16 + l15;
        int z = b * 16 + (n >> 6), d = n & 63;
        float v = acc[mi][ni][r] * scale;
        int idx = (wsel == 2) ? ((z * 64 + d) * 2048 + tt)
                              : ((z * 2048 + tt) * 64 + d);
        D[idx] = f2bf(v);
      }
    }
}

// ---------------- O projection: fp32 out, grid (8,32) ----------------------
__global__ __launch_bounds__(256, 2) void gemm_o(
    const unsigned short* __restrict__ A, const unsigned short* __restrict__ Bm,
    float* __restrict__ C) {
  constexpr int K = 1024;
  __shared__ alignas(16) unsigned short Al[128 * 32];
  __shared__ alignas(16) unsigned short Bl[128 * 32];
  const int t = threadIdx.x;
  const int l = t & 63, l15 = l & 15, l4 = l >> 4;
  const int wm = ((t >> 6) & 1) * 64, wn = (t >> 7) * 64;
  const int m0 = blockIdx.y * 128, n0 = blockIdx.x * 128;

  f32x4 zero4 = {0.f, 0.f, 0.f, 0.f};
  f32x4 acc[4][4];
#pragma unroll
  for (int i = 0; i < 4; i++)
#pragma unroll
    for (int j = 0; j < 4; j++) acc[i][j] = zero4;

  const int row0 = t >> 2, seg = (t & 3) * 8;
  const unsigned short* Ag0 = A + (m0 + row0) * K + seg;
  const unsigned short* Ag1 = A + (m0 + row0 + 64) * K + seg;
  const unsigned short* Bg0 = Bm + (n0 + row0) * K + seg;
  const unsigned short* Bg1 = Bm + (n0 + row0 + 64) * K + seg;

  for (int k0 = 0; k0 < K; k0 += 32) {
    gl2lds16(Ag0 + k0, &Al[t * 8]);
    gl2lds16(Ag1 + k0, &Al[2048 + t * 8]);
    gl2lds16(Bg0 + k0, &Bl[t * 8]);
    gl2lds16(Bg1 + k0, &Bl[2048 + t * 8]);
    __syncthreads();
    short8 af[4], bf8[4];
#pragma unroll
    for (int mi = 0; mi < 4; mi++)
      af[mi] = *(const short8*)&Al[(wm + mi * 16 + l15) * 32 + l4 * 8];
#pragma unroll
    for (int ni = 0; ni < 4; ni++)
      bf8[ni] = *(const short8*)&Bl[(wn + ni * 16 + l15) * 32 + l4 * 8];
#pragma unroll
    for (int mi = 0; mi < 4; mi++)
#pragma unroll
      for (int ni = 0; ni < 4; ni++)
        acc[mi][ni] = __builtin_amdgcn_mfma_f32_16x16x32_bf16(
            af[mi], bf8[ni], acc[mi][ni], 0, 0, 0);
    __syncthreads();
  }
#pragma unroll
  for (int mi = 0; mi < 4; mi++)
#pragma unroll
    for (int r = 0; r < 4; r++) {
      int m = m0 + wm + mi * 16 + l4 * 4 + r;
      float* cp = C + m * 1024 + n0 + wn + l15;
#pragma unroll
      for (int ni = 0; ni < 4; ni++) cp[ni * 16] = acc[mi][ni][r];
    }
}

// ---------------- Flash attention, static-margin exp2 softmax --------------
// grid 512 blocks (pair-balanced: g<256 -> qt=15-(g>>5), else qt=(g-256)>>5).
// 4 waves x 32 q-rows. K/V double-buffered (1 barrier/tile). Bias folded into
// MFMA C-init: s0 = -(slope2*qi + 10); p = exp2(s + slope2*j). l = sum(p),
// reduced once at epilogue. P round-trips LDS with XOR-swizzled segments.
__global__ __launch_bounds__(256, 3) void flash_alibi(
    const unsigned short* __restrict__ Q, const unsigned short* __restrict__ Kb,
    const unsigned short* __restrict__ Vt, unsigned short* __restrict__ O) {
  __shared__ alignas(16) unsigned short Kl[2 * 4096];
  __shared__ alignas(16) unsigned short Vl[2 * 4096];
  __shared__ alignas(16) unsigned short Pl[4 * 2304];  // 4 waves x 32 x 72
  const int t = threadIdx.x, w = t >> 6, l = t & 63, l15 = l & 15, l4 = l >> 4;
  const int g = blockIdx.x;
  const int qt = (g < 256) ? (15 - (g >> 5)) : ((g - 256) >> 5);
  const int z = g & 31;
  const int q0 = qt * 128, h = z & 15;
  const float slope2 = exp2f(-0.5f * (float)(h + 1)) * 1.4426950408889634f;
  const int qrow = q0 + w * 32;

  short8 aq[2][2];
#pragma unroll
  for (int mi = 0; mi < 2; mi++)
#pragma unroll
    for (int ks = 0; ks < 2; ks++)
      aq[mi][ks] = *(const short8*)&Q[(z * 2048 + qrow + mi * 16 + l15) * 64 +
                                      ks * 32 + l4 * 8];

  f32x4 binit[2];
#pragma unroll
  for (int mi = 0; mi < 2; mi++)
#pragma unroll
    for (int r = 0; r < 4; r++)
      binit[mi][r] =
          -(slope2 * (float)(qrow + mi * 16 + l4 * 4 + r) + 10.0f);

  f32x4 zero4 = {0.f, 0.f, 0.f, 0.f};
  f32x4 o[2][4];
  float lsum[2][4];
#pragma unroll
  for (int mi = 0; mi < 2; mi++)
#pragma unroll
    for (int j = 0; j < 4; j++) {
      o[mi][j] = zero4;
      lsum[mi][j] = 0.f;
    }

  const int row0 = t >> 2, seg8 = (t & 3) * 8;
  const int kvtiles = 2 * qt + 2;

#define ISSUE_LOADS(KV0, BUF)                                                \
  {                                                                          \
    unsigned short* Kd = &Kl[(BUF) * 4096];                                  \
    unsigned short* Vd = &Vl[(BUF) * 4096];                                  \
    gl2lds16(&Kb[(z * 2048 + (KV0) + row0) * 64 + seg8], &Kd[t * 8]);        \
    gl2lds16(&Kb[(z * 2048 + (KV0) + row0) * 64 + 32 + seg8],                \
             &Kd[2048 + t * 8]);                                             \
    gl2lds16(&Vt[(z * 64 + row0) * 2048 + (KV0) + seg8], &Vd[t * 8]);        \
    gl2lds16(&Vt[(z * 64 + row0) * 2048 + (KV0) + 32 + seg8],                \
             &Vd[2048 + t * 8]);                                             \
  }

  ISSUE_LOADS(0, 0)

  for (int it = 0; it < kvtiles; ++it) {
    __syncthreads();  // drains vmcnt -> buf (it&1) ready
    const int kv0 = it * 64;
    if (it + 1 < kvtiles) ISSUE_LOADS((it + 1) * 64, (it + 1) & 1)
    if (kv0 > qrow + 31) continue;  // fully masked for this wave
    const unsigned short* Kc = &Kl[(it & 1) * 4096];
    const unsigned short* Vc = &Vl[(it & 1) * 4096];

    // S = Q K^T + binit
    f32x4 s[2][4];
#pragma unroll
    for (int mi = 0; mi < 2; mi++)
#pragma unroll
      for (int ni = 0; ni < 4; ni++) s[mi][ni] = binit[mi];
#pragma unroll
    for (int ks = 0; ks < 2; ks++) {
      short8 bk[4];
#pragma unroll
      for (int ni = 0; ni < 4; ni++)
        bk[ni] = *(const short8*)&Kc[(ks * 64 + ni * 16 + l15) * 32 + l4 * 8];
#pragma unroll
      for (int mi = 0; mi < 2; mi++)
#pragma unroll
        for (int ni = 0; ni < 4; ni++)
          s[mi][ni] = __builtin_amdgcn_mfma_f32_16x16x32_bf16(
              aq[mi][ks], bk[ni], s[mi][ni], 0, 0, 0);
    }

    const bool needMask = (kv0 + 63 > qrow);
    float jf[4];
#pragma unroll
    for (int ni = 0; ni < 4; ni++) jf[ni] = (float)(kv0 + ni * 16 + l15);

#pragma unroll
    for (int mi = 0; mi < 2; mi++)
#pragma unroll
      for (int r = 0; r < 4; r++) {
        float ps[4];
#pragma unroll
        for (int ni = 0; ni < 4; ni++)
          ps[ni] =
              __builtin_amdgcn_exp2f(fmaf(slope2, jf[ni], s[mi][ni][r]));
        if (needMask) {
          int qi = qrow + mi * 16 + l4 * 4 + r;
#pragma unroll
          for (int ni = 0; ni < 4; ni++)
            if (kv0 + ni * 16 + l15 > qi) ps[ni] = 0.f;
        }
        lsum[mi][r] += (ps[0] + ps[1]) + (ps[2] + ps[3]);
        int row = mi * 16 + l4 * 4 + r;
        unsigned short* pp = &Pl[w * 2304 + row * 72 + (l15 & 7)];
#pragma unroll
        for (int ni = 0; ni < 4; ni++)
          pp[((ni * 2 + (l15 >> 3)) ^ l4) * 8] = f2bf(ps[ni]);
      }

    // P region is wave-private; per-wave LDS is in-order -> waitcnt suffices
    asm volatile("s_waitcnt lgkmcnt(0)" ::: "memory");

    const int rsw = (l15 >> 2) & 3;
#pragma unroll
    for (int ks = 0; ks < 2; ks++) {
      short8 pf[2], vf[4];
#pragma unroll
      for (int mi = 0; mi < 2; mi++)
        pf[mi] = *(const short8*)&Pl[w * 2304 + (mi * 16 + l15) * 72 +
                                     ((ks * 4 + l4) ^ rsw) * 8];
#pragma unroll
      for (int nd = 0; nd < 4; nd++)
        vf[nd] = *(const short8*)&Vc[(ks * 64 + nd * 16 + l15) * 32 + l4 * 8];
#pragma unroll
      for (int mi = 0; mi < 2; mi++)
#pragma unroll
        for (int nd = 0; nd < 4; nd++)
          o[mi][nd] = __builtin_amdgcn_mfma_f32_16x16x32_bf16(
              pf[mi], vf[nd], o[mi][nd], 0, 0, 0);
    }
  }
#undef ISSUE_LOADS

  // epilogue: reduce l across the 16 cols, O/l -> bf16 (b, t, h*64+d)
  const int bq = z >> 4, hh = z & 15;
#pragma unroll
  for (int mi = 0; mi < 2; mi++)
#pragma unroll
    for (int r = 0; r < 4; r++) {
      float lv = lsum[mi][r];
#pragma unroll
      for (int off = 1; off < 16; off <<= 1) lv += __shfl_xor(lv, off);
      float inv = 1.0f / lv;
      int tg = qrow + mi * 16 + l4 * 4 + r;
      unsigned short* op = &O[(bq * 2048 + tg) * 1024 + hh * 64 + l15];
#pragma unroll
      for (int nd = 0; nd < 4; nd++) op[nd * 16] = f2bf(o[mi][nd][r] * inv);
    }
}

// ---------------------------------------------------------------------------
extern "C" void kernel_launch(void* const* d_in, const int* in_sizes, int n_in,
                              void* d_out, int out_size, void* d_ws,
                              size_t ws_size, hipStream_t stream) {
  const float* x = (const float*)d_in[0];
  const float* Wq = (const float*)d_in[1];
  const float* Wk = (const float*)d_in[2];
  const float* Wv = (const float*)d_in[3];
  const float* Wo = (const float*)d_in[4];

  char* p = (char*)d_ws;
  unsigned short* xb = (unsigned short*)p;  p += 4096 * 1024 * 2;
  unsigned short* wqb = (unsigned short*)p; p += 1024 * 1024 * 2;
  unsigned short* wkb = (unsigned short*)p; p += 1024 * 1024 * 2;
  unsigned short* wvb = (unsigned short*)p; p += 1024 * 1024 * 2;
  unsigned short* wob = (unsigned short*)p; p += 1024 * 1024 * 2;
  unsigned short* Qb = (unsigned short*)p;  p += 32 * 2048 * 64 * 2;
  unsigned short* Kbf = (unsigned short*)p; p += 32 * 2048 * 64 * 2;
  unsigned short* Vtb = (unsigned short*)p; p += 32 * 2048 * 64 * 2;
  unsigned short* Ob = (unsigned short*)p;  p += 4096 * 1024 * 2;

  cvt_all<<<8192, 256, 0, stream>>>(x, Wq, Wk, Wv, Wo, xb, wqb, wkb, wvb, wob);
  gemm_qkv<<<dim3(24, 32), 256, 0, stream>>>(xb, wqb, wkb, wvb, Qb, Kbf, Vtb);
  flash_alibi<<<512, 256, 0, stream>>>(Qb, Kbf, Vtb, Ob);
  gemm_o<<<dim3(8, 32), 256, 0, stream>>>(Ob, wob, (float*)d_out);
}

// Round 5
// 178.013 us; speedup vs baseline: 1.7374x; 1.1330x over previous
//
#include <hip/hip_runtime.h>

// B=2, T=2048, D_MODEL=1024, H=16, Dh=64.  out = MHA_ALiBi(x) @ Wo^T
// cvt | fused QKV GEMM (V via LDS-transpose epilogue) | split-KV flash attn
// (static-margin exp2 softmax -> additive partials) | combine | O proj.
// R4 fix: V-transpose epilogue batch index (zg += b*16, t-offset = m0&2047).

#define DEV __device__ __forceinline__

typedef __attribute__((ext_vector_type(8))) short short8;     // 8 bf16
typedef __attribute__((ext_vector_type(4))) float f32x4;      // MFMA C/D
typedef __attribute__((ext_vector_type(4))) unsigned short ushort4v;

DEV unsigned short f2bf(float f) {                            // RNE fp32->bf16
  unsigned u = __builtin_bit_cast(unsigned, f);
  u += 0x7fffu + ((u >> 16) & 1u);
  return (unsigned short)(u >> 16);
}
DEV float bf2f(unsigned short u) {
  unsigned x = ((unsigned)u) << 16;
  return __builtin_bit_cast(float, x);
}

DEV void gl2lds16(const void* g, void* l) {                   // 16B direct-to-LDS
  __builtin_amdgcn_global_load_lds(
      (const __attribute__((address_space(1))) void*)g,
      (__attribute__((address_space(3))) void*)l, 16, 0, 0);
}

// ---------------- fused fp32 -> bf16 convert (x + 4 weights) ---------------
__global__ __launch_bounds__(256) void cvt_all(
    const float* __restrict__ x, const float* __restrict__ wq,
    const float* __restrict__ wk, const float* __restrict__ wv,
    const float* __restrict__ wo, unsigned short* __restrict__ xb,
    unsigned short* __restrict__ wqb, unsigned short* __restrict__ wkb,
    unsigned short* __restrict__ wvb, unsigned short* __restrict__ wob) {
  int b = blockIdx.x;
  const float* s;
  unsigned short* d;
  int off;
  if (b < 4096)      { s = x;  d = xb;  off = b; }
  else if (b < 5120) { s = wq; d = wqb; off = b - 4096; }
  else if (b < 6144) { s = wk; d = wkb; off = b - 5120; }
  else if (b < 7168) { s = wv; d = wvb; off = b - 6144; }
  else               { s = wo; d = wob; off = b - 7168; }
  int i = (off * 256 + threadIdx.x) * 4;
  float4 v = *(const float4*)(s + i);
  ushort4v o = {f2bf(v.x), f2bf(v.y), f2bf(v.z), f2bf(v.w)};
  *(ushort4v*)(d + i) = o;
}

// ---------------- fused QKV GEMM: C[m,n] = sum_k A[m,k]*W[n,k] -------------
// grid (24, 32): wsel = x>>3. 128x128 tile, BK=32, m97 structure.
// wsel 0: Q (scale log2e/8, (z,t,d)) | 1: K ((z,t,d)) | 2: V (z,d,t) via
// LDS-transpose epilogue with coalesced 16B stores.
__global__ __launch_bounds__(256, 2) void gemm_qkv(
    const unsigned short* __restrict__ A, const unsigned short* __restrict__ Wq,
    const unsigned short* __restrict__ Wk, const unsigned short* __restrict__ Wv,
    unsigned short* __restrict__ Qo, unsigned short* __restrict__ Ko,
    unsigned short* __restrict__ Vo) {
  constexpr int K = 1024;
  __shared__ alignas(16) unsigned short Sm[18432];  // staging 8K | transpose 18.4K
  unsigned short* Al = Sm;
  unsigned short* Bl = Sm + 4096;
  const int t = threadIdx.x;
  const int l = t & 63, l15 = l & 15, l4 = l >> 4;
  const int wm = ((t >> 6) & 1) * 64, wn = (t >> 7) * 64;
  const int wsel = blockIdx.x >> 3;
  const int n0 = (blockIdx.x & 7) * 128;
  const int m0 = blockIdx.y * 128;
  const unsigned short* Bm = (wsel == 0) ? Wq : ((wsel == 1) ? Wk : Wv);

  f32x4 zero4 = {0.f, 0.f, 0.f, 0.f};
  f32x4 acc[4][4];
#pragma unroll
  for (int i = 0; i < 4; i++)
#pragma unroll
    for (int j = 0; j < 4; j++) acc[i][j] = zero4;

  const int row0 = t >> 2, seg = (t & 3) * 8;
  const unsigned short* Ag0 = A + (m0 + row0) * K + seg;
  const unsigned short* Ag1 = A + (m0 + row0 + 64) * K + seg;
  const unsigned short* Bg0 = Bm + (n0 + row0) * K + seg;
  const unsigned short* Bg1 = Bm + (n0 + row0 + 64) * K + seg;

  for (int k0 = 0; k0 < K; k0 += 32) {
    gl2lds16(Ag0 + k0, &Al[t * 8]);
    gl2lds16(Ag1 + k0, &Al[2048 + t * 8]);
    gl2lds16(Bg0 + k0, &Bl[t * 8]);
    gl2lds16(Bg1 + k0, &Bl[2048 + t * 8]);
    __syncthreads();
    short8 af[4], bf8[4];
#pragma unroll
    for (int mi = 0; mi < 4; mi++)
      af[mi] = *(const short8*)&Al[(wm + mi * 16 + l15) * 32 + l4 * 8];
#pragma unroll
    for (int ni = 0; ni < 4; ni++)
      bf8[ni] = *(const short8*)&Bl[(wn + ni * 16 + l15) * 32 + l4 * 8];
#pragma unroll
    for (int mi = 0; mi < 4; mi++)
#pragma unroll
      for (int ni = 0; ni < 4; ni++)
        acc[mi][ni] = __builtin_amdgcn_mfma_f32_16x16x32_bf16(
            af[mi], bf8[ni], acc[mi][ni], 0, 0, 0);
    __syncthreads();
  }

  if (wsel != 2) {
    unsigned short* D = (wsel == 0) ? Qo : Ko;
    const float scale = (wsel == 0) ? 0.18033688011112042f : 1.0f;  // log2e/8
#pragma unroll
    for (int mi = 0; mi < 4; mi++)
#pragma unroll
      for (int r = 0; r < 4; r++) {
        int m = m0 + wm + mi * 16 + l4 * 4 + r;
        int b = m >> 11, tt = m & 2047;
#pragma unroll
        for (int ni = 0; ni < 4; ni++) {
          int n = n0 + wn + ni * 16 + l15;
          int z = b * 16 + (n >> 6), d = n & 63;
          D[(z * 2048 + tt) * 64 + d] = f2bf(acc[mi][ni][r] * scale);
        }
      }
  } else {
    // V: write acc into per-wave LDS region [d 64][t 64] stride 72, then
    // coalesced 16B stores along t.
    unsigned short* Tr = Sm + (t >> 6) * 4608;
#pragma unroll
    for (int mi = 0; mi < 4; mi++)
#pragma unroll
      for (int r = 0; r < 4; r++) {
        int tl = mi * 16 + l4 * 4 + r;
#pragma unroll
        for (int ni = 0; ni < 4; ni++)
          Tr[(ni * 16 + l15) * 72 + tl] = f2bf(acc[mi][ni][r]);
      }
    __syncthreads();
    // 2048 16B-chunks: row(0..127)={zh,d}, c = t-chunk(0..15); wave = 2*zh+(c>>3)
    const int bb = m0 >> 11, tbase = m0 & 2047;  // R4 fix: batch-aware dest
#pragma unroll
    for (int it2 = 0; it2 < 8; it2++) {
      int idx = it2 * 256 + t;
      int row = idx >> 4, c = idx & 15;
      int zh = row >> 6, dd = row & 63;
      int wsrc = zh * 2 + (c >> 3);
      short8 v = *(const short8*)&Sm[wsrc * 4608 + dd * 72 + (c & 7) * 8];
      int zg = bb * 16 + (n0 >> 6) + zh;
      *(short8*)&Vo[(zg * 64 + dd) * 2048 + tbase + c * 8] = v;
    }
  }
}

// ---------------- O projection: 128x64 tiles, grid (16,32) = 512 blocks ----
__global__ __launch_bounds__(256, 2) void gemm_o(
    const unsigned short* __restrict__ A, const unsigned short* __restrict__ Bm,
    float* __restrict__ C) {
  constexpr int K = 1024;
  __shared__ alignas(16) unsigned short Al[128 * 32];
  __shared__ alignas(16) unsigned short Bl[64 * 32];
  const int t = threadIdx.x;
  const int l = t & 63, l15 = l & 15, l4 = l >> 4;
  const int wm = ((t >> 6) & 1) * 64, wn = (t >> 7) * 32;
  const int m0 = blockIdx.y * 128, n0 = blockIdx.x * 64;

  f32x4 zero4 = {0.f, 0.f, 0.f, 0.f};
  f32x4 acc[4][2];
#pragma unroll
  for (int i = 0; i < 4; i++)
#pragma unroll
    for (int j = 0; j < 2; j++) acc[i][j] = zero4;

  const int row0 = t >> 2, seg = (t & 3) * 8;
  const unsigned short* Ag0 = A + (m0 + row0) * K + seg;
  const unsigned short* Ag1 = A + (m0 + row0 + 64) * K + seg;
  const unsigned short* Bg0 = Bm + (n0 + row0) * K + seg;

  for (int k0 = 0; k0 < K; k0 += 32) {
    gl2lds16(Ag0 + k0, &Al[t * 8]);
    gl2lds16(Ag1 + k0, &Al[2048 + t * 8]);
    gl2lds16(Bg0 + k0, &Bl[t * 8]);
    __syncthreads();
    short8 af[4], bf2[2];
#pragma unroll
    for (int mi = 0; mi < 4; mi++)
      af[mi] = *(const short8*)&Al[(wm + mi * 16 + l15) * 32 + l4 * 8];
#pragma unroll
    for (int ni = 0; ni < 2; ni++)
      bf2[ni] = *(const short8*)&Bl[(wn + ni * 16 + l15) * 32 + l4 * 8];
#pragma unroll
    for (int mi = 0; mi < 4; mi++)
#pragma unroll
      for (int ni = 0; ni < 2; ni++)
        acc[mi][ni] = __builtin_amdgcn_mfma_f32_16x16x32_bf16(
            af[mi], bf2[ni], acc[mi][ni], 0, 0, 0);
    __syncthreads();
  }
#pragma unroll
  for (int mi = 0; mi < 4; mi++)
#pragma unroll
    for (int r = 0; r < 4; r++) {
      int m = m0 + wm + mi * 16 + l4 * 4 + r;
      float* cp = C + m * 1024 + n0 + wn + l15;
      cp[0] = acc[mi][0][r];
      cp[16] = acc[mi][1][r];
    }
}

// ---------------- Split-KV flash attention ---------------------------------
// grid 1024: qt = 15-(g>>6) (heavy first); z = (g&63)>>1; s = g&1.
// Side s covers kv tiles [s?qt+1:0 .. s?2qt+1:qt] — exactly qt+1 tiles each.
// Static-margin softmax (no running max) => partials combine additively.
// Masking/skip are SIDE-AGNOSTIC: qt=0 side 0 touches the diagonal.
__global__ __launch_bounds__(256, 3) void flash_alibi(
    const unsigned short* __restrict__ Q, const unsigned short* __restrict__ Kb,
    const unsigned short* __restrict__ Vt, unsigned short* __restrict__ O0,
    unsigned short* __restrict__ O1, float* __restrict__ L0,
    float* __restrict__ L1) {
  __shared__ alignas(16) unsigned short Kl[2 * 4096];
  __shared__ alignas(16) unsigned short Vl[2 * 4096];
  __shared__ alignas(16) unsigned short Pl[4 * 2304];  // 4 waves x 32 x 72
  const int t = threadIdx.x, w = t >> 6, l = t & 63, l15 = l & 15, l4 = l >> 4;
  const int g = blockIdx.x;
  const int qt = 15 - (g >> 6);
  const int z = (g & 63) >> 1, s = g & 1;
  const int q0 = qt * 128, h = z & 15;
  const float slope2 = exp2f(-0.5f * (float)(h + 1)) * 1.4426950408889634f;
  const int qrow = q0 + w * 32;

  short8 aq[2][2];
#pragma unroll
  for (int mi = 0; mi < 2; mi++)
#pragma unroll
    for (int ks = 0; ks < 2; ks++)
      aq[mi][ks] = *(const short8*)&Q[(z * 2048 + qrow + mi * 16 + l15) * 64 +
                                      ks * 32 + l4 * 8];

  f32x4 binit[2];
#pragma unroll
  for (int mi = 0; mi < 2; mi++)
#pragma unroll
    for (int r = 0; r < 4; r++)
      binit[mi][r] = -(slope2 * (float)(qrow + mi * 16 + l4 * 4 + r) + 10.0f);

  f32x4 zero4 = {0.f, 0.f, 0.f, 0.f};
  f32x4 o[2][4];
  float lsum[2][4];
#pragma unroll
  for (int mi = 0; mi < 2; mi++)
#pragma unroll
    for (int j = 0; j < 4; j++) {
      o[mi][j] = zero4;
      lsum[mi][j] = 0.f;
    }

  const int row0 = t >> 2, seg8 = (t & 3) * 8;
  const int it0 = s ? (qt + 1) : 0;
  const int nt = qt + 1;

#define ISSUE_LOADS(KV0, BUF)                                                \
  {                                                                          \
    unsigned short* Kd = &Kl[(BUF) * 4096];                                  \
    unsigned short* Vd = &Vl[(BUF) * 4096];                                  \
    gl2lds16(&Kb[(z * 2048 + (KV0) + row0) * 64 + seg8], &Kd[t * 8]);        \
    gl2lds16(&Kb[(z * 2048 + (KV0) + row0) * 64 + 32 + seg8],                \
             &Kd[2048 + t * 8]);                                             \
    gl2lds16(&Vt[(z * 64 + row0) * 2048 + (KV0) + seg8], &Vd[t * 8]);        \
    gl2lds16(&Vt[(z * 64 + row0) * 2048 + (KV0) + 32 + seg8],                \
             &Vd[2048 + t * 8]);                                             \
  }

  ISSUE_LOADS(it0 * 64, 0)

  for (int ii = 0; ii < nt; ++ii) {
    __syncthreads();  // buf (ii&1) ready
    const int kv0 = (it0 + ii) * 64;
    if (ii + 1 < nt) ISSUE_LOADS(kv0 + 64, (ii + 1) & 1)
    if (kv0 > qrow + 31) continue;  // fully masked for this wave
    const unsigned short* Kc = &Kl[(ii & 1) * 4096];
    const unsigned short* Vc = &Vl[(ii & 1) * 4096];

    f32x4 sc[2][4];
#pragma unroll
    for (int mi = 0; mi < 2; mi++)
#pragma unroll
      for (int ni = 0; ni < 4; ni++) sc[mi][ni] = binit[mi];
#pragma unroll
    for (int ks = 0; ks < 2; ks++) {
      short8 bk[4];
#pragma unroll
      for (int ni = 0; ni < 4; ni++)
        bk[ni] = *(const short8*)&Kc[(ks * 64 + ni * 16 + l15) * 32 + l4 * 8];
#pragma unroll
      for (int mi = 0; mi < 2; mi++)
#pragma unroll
        for (int ni = 0; ni < 4; ni++)
          sc[mi][ni] = __builtin_amdgcn_mfma_f32_16x16x32_bf16(
              aq[mi][ks], bk[ni], sc[mi][ni], 0, 0, 0);
    }

    const bool needMask = (kv0 + 63 > qrow);  // diagonal tile (either side)
    float jf[4];
#pragma unroll
    for (int ni = 0; ni < 4; ni++) jf[ni] = (float)(kv0 + ni * 16 + l15);

#pragma unroll
    for (int mi = 0; mi < 2; mi++)
#pragma unroll
      for (int r = 0; r < 4; r++) {
        float ps[4];
#pragma unroll
        for (int ni = 0; ni < 4; ni++)
          ps[ni] = __builtin_amdgcn_exp2f(fmaf(slope2, jf[ni], sc[mi][ni][r]));
        if (needMask) {
          int qi = qrow + mi * 16 + l4 * 4 + r;
#pragma unroll
          for (int ni = 0; ni < 4; ni++)
            if (kv0 + ni * 16 + l15 > qi) ps[ni] = 0.f;
        }
        lsum[mi][r] += (ps[0] + ps[1]) + (ps[2] + ps[3]);
        int row = mi * 16 + l4 * 4 + r;
        unsigned short* pp = &Pl[w * 2304 + row * 72 + (l15 & 7)];
#pragma unroll
        for (int ni = 0; ni < 4; ni++)
          pp[((ni * 2 + (l15 >> 3)) ^ l4) * 8] = f2bf(ps[ni]);
      }

    asm volatile("s_waitcnt lgkmcnt(0)" ::: "memory");  // wave-private P region

    const int rsw = (l15 >> 2) & 3;
#pragma unroll
    for (int ks = 0; ks < 2; ks++) {
      short8 pf[2], vf[4];
#pragma unroll
      for (int mi = 0; mi < 2; mi++)
        pf[mi] = *(const short8*)&Pl[w * 2304 + (mi * 16 + l15) * 72 +
                                     ((ks * 4 + l4) ^ rsw) * 8];
#pragma unroll
      for (int nd = 0; nd < 4; nd++)
        vf[nd] = *(const short8*)&Vc[(ks * 64 + nd * 16 + l15) * 32 + l4 * 8];
#pragma unroll
      for (int mi = 0; mi < 2; mi++)
#pragma unroll
        for (int nd = 0; nd < 4; nd++)
          o[mi][nd] = __builtin_amdgcn_mfma_f32_16x16x32_bf16(
              pf[mi], vf[nd], o[mi][nd], 0, 0, 0);
    }
  }
#undef ISSUE_LOADS

  // epilogue: write PARTIAL O (no normalization) + partial l
  unsigned short* Op = s ? O1 : O0;
  float* Lp = s ? L1 : L0;
#pragma unroll
  for (int mi = 0; mi < 2; mi++)
#pragma unroll
    for (int r = 0; r < 4; r++) {
      float lv = lsum[mi][r];
#pragma unroll
      for (int off = 1; off < 16; off <<= 1) lv += __shfl_xor(lv, off);
      int tg = qrow + mi * 16 + l4 * 4 + r;
      if (l15 == 0) Lp[z * 2048 + tg] = lv;
      unsigned short* op = &Op[(z * 2048 + tg) * 64 + l15];
#pragma unroll
      for (int nd = 0; nd < 4; nd++) op[nd * 16] = f2bf(o[mi][nd][r]);
    }
}

// ---------------- combine: O=(O0+O1)/(l0+l1), (z,t,d) -> (b,t,h*64+d) ------
__global__ __launch_bounds__(256) void combine(
    const unsigned short* __restrict__ O0, const unsigned short* __restrict__ O1,
    const float* __restrict__ L0, const float* __restrict__ L1,
    unsigned short* __restrict__ Ob) {
  int idx = (blockIdx.x * 256 + threadIdx.x) * 8;  // flat (z,t,d)
  int z = idx >> 17, rem = idx & 131071;
  int tt = rem >> 6, d = rem & 63;
  short8 a = *(const short8*)(O0 + idx);
  short8 b = *(const short8*)(O1 + idx);
  float inv = 1.0f / (L0[z * 2048 + tt] + L1[z * 2048 + tt]);
  short8 o;
#pragma unroll
  for (int j = 0; j < 8; j++) {
    float v = (bf2f((unsigned short)a[j]) + bf2f((unsigned short)b[j])) * inv;
    o[j] = (short)f2bf(v);
  }
  int bq = z >> 4, h = z & 15;
  *(short8*)(Ob + (bq * 2048 + tt) * 1024 + h * 64 + d) = o;
}

// ---------------------------------------------------------------------------
extern "C" void kernel_launch(void* const* d_in, const int* in_sizes, int n_in,
                              void* d_out, int out_size, void* d_ws,
                              size_t ws_size, hipStream_t stream) {
  const float* x = (const float*)d_in[0];
  const float* Wq = (const float*)d_in[1];
  const float* Wk = (const float*)d_in[2];
  const float* Wv = (const float*)d_in[3];
  const float* Wo = (const float*)d_in[4];

  char* p = (char*)d_ws;
  unsigned short* xb = (unsigned short*)p;  p += 4096 * 1024 * 2;  // O0 after qkv
  unsigned short* wqb = (unsigned short*)p; p += 1024 * 1024 * 2;
  unsigned short* wkb = (unsigned short*)p; p += 1024 * 1024 * 2;
  unsigned short* wvb = (unsigned short*)p; p += 1024 * 1024 * 2;
  unsigned short* wob = (unsigned short*)p; p += 1024 * 1024 * 2;
  unsigned short* Qb = (unsigned short*)p;  p += 32 * 2048 * 64 * 2;  // Ob after flash
  unsigned short* Kbf = (unsigned short*)p; p += 32 * 2048 * 64 * 2;
  unsigned short* Vtb = (unsigned short*)p; p += 32 * 2048 * 64 * 2;
  unsigned short* O1 = (unsigned short*)p;  p += 32 * 2048 * 64 * 2;
  float* L0 = (float*)p;                    p += 32 * 2048 * 4;
  float* L1 = (float*)p;                    p += 32 * 2048 * 4;
  unsigned short* O0 = xb;  // xb dead after gemm_qkv
  unsigned short* Ob = Qb;  // Qb dead after flash

  cvt_all<<<8192, 256, 0, stream>>>(x, Wq, Wk, Wv, Wo, xb, wqb, wkb, wvb, wob);
  gemm_qkv<<<dim3(24, 32), 256, 0, stream>>>(xb, wqb, wkb, wvb, Qb, Kbf, Vtb);
  flash_alibi<<<1024, 256, 0, stream>>>(Qb, Kbf, Vtb, O0, O1, L0, L1);
  combine<<<2048, 256, 0, stream>>>(O0, O1, L0, L1, Ob);
  gemm_o<<<dim3(16, 32), 256, 0, stream>>>(Ob, wob, (float*)d_out);
}